// Round 11
// baseline (133.866 us; speedup 1.0000x reference)
//
#include <hip/hip_runtime.h>

#define NB 8
#define SS 2048
#define HH 512
#define NSTY 128
#define SP (SS + 2)
#define EPSF 1e-5f

#define BM 128
#define BN 128

typedef __attribute__((ext_vector_type(8))) short short8;
typedef __attribute__((ext_vector_type(4))) float floatx4;
typedef __attribute__((ext_vector_type(4))) unsigned short u16x4;
typedef unsigned short u16;

__device__ __forceinline__ float bf2f(u16 u) {
  union { float f; unsigned int i; } v; v.i = ((unsigned int)u) << 16; return v.f;
}
__device__ __forceinline__ u16 f2bf(float f) {
  union { float f; unsigned int i; } v; v.f = f;
  unsigned int x = v.i;
  return (u16)((x + 0x7fffu + ((x >> 16) & 1u)) >> 16);
}
__device__ __forceinline__ float lrelu(float v) { return v >= 0.f ? v : 0.2f * v; }

__device__ __forceinline__ void gld_lds16(const u16* g, u16* l) {
  __builtin_amdgcn_global_load_lds((const __attribute__((address_space(1))) void*)g,
                                   (__attribute__((address_space(3))) void*)l, 16, 0, 0);
}

// ---------------- zero stats ----------------
__global__ void k_zero(float* p, int n) {
  int i = blockIdx.x * 256 + threadIdx.x;
  if (i < n) p[i] = 0.f;
}

// ---------------- style projections (both) ----------------
__global__ void k_proj(const float* style, const float* w1, const float* b1,
                       const float* w2, const float* b2,
                       float* g1, float* be1, float* g2, float* be2) {
  int idx = blockIdx.x * 256 + threadIdx.x;         // 2 * NB * 2H
  if (idx >= 2 * NB * 2 * HH) return;
  int which = idx / (NB * 2 * HH);
  int r = idx % (NB * 2 * HH);
  int b = r / (2 * HH);
  int j = r % (2 * HH);
  const float* w = which ? w2 : w1;
  const float* bias = which ? b2 : b1;
  float acc = bias[j];
  const float* st = style + b * NSTY;
  const float* wr = w + j * NSTY;
  for (int t = 0; t < NSTY; t++) acc += st[t] * wr[t];
  float* gd = which ? g2 : g1;
  float* bd = which ? be2 : be1;
  if (j < HH) gd[b * HH + j] = acc;
  else        bd[b * HH + (j - HH)] = acc;
}

// ---------------- weight norm + repack to bf16 [k][o][i] ----------------
__global__ void k_wnorm(const float* v1, const float* g1, const float* v2, const float* g2,
                        u16* wt1, u16* wt2) {
  int o = blockIdx.x % HH;
  int which = blockIdx.x / HH;
  const float* v = which ? v2 : v1;
  const float* g = which ? g2 : g1;
  u16* wt = which ? wt2 : wt1;
  float s = 0.f;
  for (int e = threadIdx.x; e < HH * 3; e += 256) {
    float x = v[o * HH * 3 + e];
    s += x * x;
  }
  for (int off = 32; off > 0; off >>= 1) s += __shfl_down(s, off, 64);
  __shared__ float red[4];
  int wid = threadIdx.x >> 6, lane = threadIdx.x & 63;
  if (lane == 0) red[wid] = s;
  __syncthreads();
  float tot = red[0] + red[1] + red[2] + red[3];
  float scale = g[o] / sqrtf(tot);
  for (int e = threadIdx.x; e < HH * 3; e += 256) {
    int i = e / 3, k = e % 3;      // v[o][i][k] flat = o*1536 + e
    wt[(k * HH + o) * HH + i] = f2bf(v[o * HH * 3 + e] * scale);
  }
}

// ---------------- masked stats over S (f32 input), latency-fixed ----------------
#define SSPLIT1 64
__global__ void k_stats_f32(const float* __restrict__ x, const int* __restrict__ lens,
                            float* __restrict__ sum, float* __restrict__ sumsq) {
  int b = blockIdx.x & 7;
  int chunk = blockIdx.x >> 3;                     // 0..63
  int s0 = chunk * (SS / SSPLIT1);                 // 32 rows per block
  int h4 = (threadIdx.x & 127) * 4;                // float4 column
  int sr = threadIdx.x >> 7;                       // 0,1
  int len = lens[b];
  float4 sm = {0.f, 0.f, 0.f, 0.f}, sq = {0.f, 0.f, 0.f, 0.f};
#pragma unroll
  for (int i = 0; i < 16; i++) {
    int s = s0 + i * 2 + sr;
    float4 v = *(const float4*)(x + ((long)(b * SS + s)) * HH + h4);
    float m = (s < len) ? 1.f : 0.f;
    v.x *= m; v.y *= m; v.z *= m; v.w *= m;
    sm.x += v.x; sm.y += v.y; sm.z += v.z; sm.w += v.w;
    sq.x += v.x * v.x; sq.y += v.y * v.y; sq.z += v.z * v.z; sq.w += v.w * v.w;
  }
  atomicAdd(&sum[b * HH + h4 + 0], sm.x);
  atomicAdd(&sum[b * HH + h4 + 1], sm.y);
  atomicAdd(&sum[b * HH + h4 + 2], sm.z);
  atomicAdd(&sum[b * HH + h4 + 3], sm.w);
  atomicAdd(&sumsq[b * HH + h4 + 0], sq.x);
  atomicAdd(&sumsq[b * HH + h4 + 1], sq.y);
  atomicAdd(&sumsq[b * HH + h4 + 2], sq.z);
  atomicAdd(&sumsq[b * HH + h4 + 3], sq.w);
}

// ---------------- adain affine from raw stats (inline helper) ----------------
__device__ __forceinline__ void affine4(const float* sum, const float* sumsq,
                                        const float* gam, const float* bet,
                                        int b, int i, float cnt,
                                        float4& av, float4& cv) {
  float4 sm = *(const float4*)(sum + b * HH + i);
  float4 sq = *(const float4*)(sumsq + b * HH + i);
  float4 gv = *(const float4*)(gam + b * HH + i);
  float4 bv = *(const float4*)(bet + b * HH + i);
  float rc = 1.f / cnt;
  float mx = sm.x * rc, my = sm.y * rc, mz = sm.z * rc, mw = sm.w * rc;
  av.x = (1.f + gv.x) * rsqrtf(sq.x * rc - mx * mx + EPSF);
  av.y = (1.f + gv.y) * rsqrtf(sq.y * rc - my * my + EPSF);
  av.z = (1.f + gv.z) * rsqrtf(sq.z * rc - mz * mz + EPSF);
  av.w = (1.f + gv.w) * rsqrtf(sq.w * rc - mw * mw + EPSF);
  cv.x = bv.x - mx * av.x;
  cv.y = bv.y - my * av.y;
  cv.z = bv.z - mz * av.z;
  cv.w = bv.w - mw * av.w;
}

// ---------------- Z prep (f32 src), fused affine, XCD-aligned ----------------
__global__ void k_prep_f32(const float* __restrict__ x,
                           const float* __restrict__ sum, const float* __restrict__ sumsq,
                           const float* __restrict__ gam, const float* __restrict__ bet,
                           const int* __restrict__ lens, u16* __restrict__ z) {
  int b = blockIdx.x & 7;
  int v = (blockIdx.x >> 3) * 256 + threadIdx.x;   // 0..262399 (exact)
  long off = (long)v * 4;                          // elem offset within batch
  int i = (int)(off % HH);
  int r = (int)(off / HH);                         // 0..SP-1
  int s = r - 1;
  int len = lens[b];
  u16x4 outv;
  if (s < 0 || s >= SS || s >= len) {
    outv = (u16x4){0, 0, 0, 0};
  } else {
    float4 av, cv;
    affine4(sum, sumsq, gam, bet, b, i, (float)len, av, cv);
    const float4 xv = *(const float4*)(x + ((long)(b * SS + s)) * HH + i);
    outv.x = f2bf(lrelu(av.x * xv.x + cv.x));
    outv.y = f2bf(lrelu(av.y * xv.y + cv.y));
    outv.z = f2bf(lrelu(av.z * xv.z + cv.z));
    outv.w = f2bf(lrelu(av.w * xv.w + cv.w));
  }
  *(u16x4*)(z + ((long)(b * SP + r)) * HH + i) = outv;
}

// ---------------- Z prep (bf16 src), fused affine, XCD-aligned ----------------
__global__ void k_prep_bf16(const u16* __restrict__ y,
                            const float* __restrict__ sum, const float* __restrict__ sumsq,
                            const float* __restrict__ gam, const float* __restrict__ bet,
                            const int* __restrict__ lens, u16* __restrict__ z) {
  int b = blockIdx.x & 7;
  int v = (blockIdx.x >> 3) * 256 + threadIdx.x;
  long off = (long)v * 4;
  int i = (int)(off % HH);
  int r = (int)(off / HH);
  int s = r - 1;
  int len = lens[b];
  u16x4 outv;
  if (s < 0 || s >= SS || s >= len) {
    outv = (u16x4){0, 0, 0, 0};
  } else {
    float4 av, cv;
    affine4(sum, sumsq, gam, bet, b, i, (float)len, av, cv);
    const u16x4 yv = *(const u16x4*)(y + ((long)(b * SS + s)) * HH + i);
    outv.x = f2bf(lrelu(av.x * bf2f(yv.x) + cv.x));
    outv.y = f2bf(lrelu(av.y * bf2f(yv.y) + cv.y));
    outv.z = f2bf(lrelu(av.z * bf2f(yv.z) + cv.z));
    outv.w = f2bf(lrelu(av.w * bf2f(yv.w) + cv.w));
  }
  *(u16x4*)(z + ((long)(b * SP + r)) * HH + i) = outv;
}

// ---------------- conv1d flat GEMM: split-K + counted-vmcnt dbuf pipeline -----
// R10 post-mortem: split-K landed 44.5 us, but 72% of each K-step is the
// stage -> vmcnt(0)-drain -> barrier serial overhead (matches m233's 2-phase
// stall). THIS ROUND (T4): within each team, 24 steps of BK=32, double-
// buffered (2 x 8KB A + 2 x 8KB B per team, 64 KB total unchanged), stage(t+1)
// issued BEFORE compute(t), s_waitcnt vmcnt(4) (counted -- the 4 newest loads
// stay in flight across the barrier), raw s_barrier x2 per step, vmcnt(0)
// only at the tail. setprio(1) around the MFMA cluster (T5: split schedule).
// LDS swizzle for 32-col tiles: pair-row involution -- position p = (r&1)*4+s
// within the 128B line (line = r>>1), stored at p^(line&7); applied to BOTH
// the pre-swizzled global source (linear LDS dest, m104 constraint) and the
// ds_read address. 16-lane read groups hit each 16B slot exactly 2x -> free.
// Split-K reduction + literal-index epilogue unchanged from R10 (rule #20).
__global__ __launch_bounds__(512, 4) void k_conv(const u16* __restrict__ z,
                                                 const u16* __restrict__ wt,
                                                 const float* __restrict__ bias,
                                                 const int* __restrict__ lens,
                                                 u16* __restrict__ yout,
                                                 const float* __restrict__ resid,
                                                 float* __restrict__ fout,
                                                 float* __restrict__ sum,
                                                 float* __restrict__ sumsq) {
  // [team][buf][A=0/B=1][128 rows x 32 cols] = 64 KB (also f32 scratch)
  __shared__ __align__(16) u16 L[2][2][2][BM * 32];

  int nwg = gridDim.x;                        // 512, divisible by 8
  int bid = blockIdx.x;
  int t = (bid & 7) * (nwg >> 3) + (bid >> 3);     // XCD-contiguous logical id
  int bn0 = (t % (HH / BN)) * BN; t /= (HH / BN);
  int bm0 = (t % (SS / BM)) * BM; t /= (SS / BM);
  int b = t;                                  // == XCD id (one batch per XCD)

  int tid = threadIdx.x;
  int wave = tid >> 6, lane = tid & 63;
  int team = wave >> 2;                       // 0: K 0..767, 1: K 768..1535
  int tw = wave & 3;
  int wr = tw >> 1, wc = tw & 1;              // team-internal 2x2 waves (64x64)
  int l15 = lane & 15, l4 = lane >> 4;

  int t256 = tid & 255;                       // index within team

  u16* A0 = &L[team][0][0][0];
  u16* B0 = &L[team][0][1][0];
  u16* A1 = &L[team][1][0][0];
  u16* B1 = &L[team][1][1][0];

  const u16* zb = z + (size_t)b * SP * HH;
  int len = lens[b];

  floatx4 acc[4][4] = {};

  // stage BK32 step st (absolute, 0..47) into (dA,dB): 4 gld/thread (uniform)
  auto stage = [&](u16* dA, u16* dB, int st) {
    int k0 = st * 32;
    const u16* wkb = wt + (size_t)(k0 >> 9) * HH * HH + (k0 & 511);
#pragma unroll
    for (int i = 0; i < 2; i++) {
      int g = i * 256 + t256;                 // 16B slot 0..511
      int line = g >> 3, pp = g & 7;
      int p = pp ^ (line & 7);
      int r = line * 2 + (p >> 2), s = p & 3;
      gld_lds16(zb + (size_t)(bm0 + r) * HH + k0 + s * 8, dA + g * 8);
    }
#pragma unroll
    for (int i = 0; i < 2; i++) {
      int g = i * 256 + t256;
      int line = g >> 3, pp = g & 7;
      int p = pp ^ (line & 7);
      int r = line * 2 + (p >> 2), s = p & 3;
      gld_lds16(wkb + (size_t)(bn0 + r) * HH + s * 8, dB + g * 8);
    }
  };

  auto compute = [&](const u16* sA, const u16* sB) {
    short8 afr[4], bfr[4];
#pragma unroll
    for (int i = 0; i < 4; i++) {
      int ar = wr * 64 + i * 16 + l15;
      afr[i] = *(const short8*)&sA[(ar >> 1) * 64 + ((((ar & 1) * 4 + l4) ^ ((ar >> 1) & 7)) * 8)];
    }
#pragma unroll
    for (int j = 0; j < 4; j++) {
      int br = wc * 64 + j * 16 + l15;
      bfr[j] = *(const short8*)&sB[(br >> 1) * 64 + ((((br & 1) * 4 + l4) ^ ((br >> 1) & 7)) * 8)];
    }
    __builtin_amdgcn_s_setprio(1);
#pragma unroll
    for (int am = 0; am < 4; am++)
#pragma unroll
      for (int bn = 0; bn < 4; bn++)
        acc[am][bn] = __builtin_amdgcn_mfma_f32_16x16x32_bf16(afr[am], bfr[bn], acc[am][bn], 0, 0, 0);
    __builtin_amdgcn_s_setprio(0);
  };

  int st0 = team * 24;                        // this team's 24 BK32 steps
  stage(A0, B0, st0);                         // 4 outstanding
  for (int tp = 0; tp < 12; tp++) {
    // even step 2tp: compute buf0, prefetch 2tp+1 into buf1
    stage(A1, B1, st0 + 2 * tp + 1);          // 8 outstanding
    asm volatile("s_waitcnt vmcnt(4)" ::: "memory");  // step 2tp landed
    __builtin_amdgcn_s_barrier();
    compute(A0, B0);
    __builtin_amdgcn_s_barrier();             // buf0 free for overwrite
    // odd step 2tp+1: compute buf1, prefetch 2tp+2 into buf0
    if (tp < 11) {
      stage(A0, B0, st0 + 2 * tp + 2);
      asm volatile("s_waitcnt vmcnt(4)" ::: "memory");
    } else {
      asm volatile("s_waitcnt vmcnt(0)" ::: "memory");
    }
    __builtin_amdgcn_s_barrier();
    compute(A1, B1);
    if (tp < 11) __builtin_amdgcn_s_barrier();
  }
  __syncthreads();                            // all reads done before scratch reuse

  // ---- cross-team reduction via LDS (reused as f32 scratch) ----
  // STATIC acc indices only (rule #20): team 0 exports cols 2,3; team 1
  // exports cols 0,1. layout: scr[team*2048 + (am*2+bnl)*256 + t256]
  floatx4* scr = (floatx4*)&L[0][0][0][0];    // 4096 float4 = 64 KB
  floatx4* my = scr + (size_t)team * 2048;
  if (team == 0) {
#pragma unroll
    for (int am = 0; am < 4; am++) {
      my[(am * 2 + 0) * 256 + t256] = acc[am][2];
      my[(am * 2 + 1) * 256 + t256] = acc[am][3];
    }
  } else {
#pragma unroll
    for (int am = 0; am < 4; am++) {
      my[(am * 2 + 0) * 256 + t256] = acc[am][0];
      my[(am * 2 + 1) * 256 + t256] = acc[am][1];
    }
  }
  __syncthreads();
  const floatx4* other = scr + (size_t)(team ^ 1) * 2048;
  if (team == 0) {
#pragma unroll
    for (int am = 0; am < 4; am++) {
      acc[am][0] += other[(am * 2 + 0) * 256 + t256];
      acc[am][1] += other[(am * 2 + 1) * 256 + t256];
    }
  } else {
#pragma unroll
    for (int am = 0; am < 4; am++) {
      acc[am][2] += other[(am * 2 + 0) * 256 + t256];
      acc[am][3] += other[(am * 2 + 1) * 256 + t256];
    }
  }

  // ---- epilogue: literal BN via macro, team branch is wave-uniform ----
#define EPI(BN) do {                                                         \
    int o = bn0 + wc * 64 + (BN) * 16 + l15;                                 \
    float bv = bias[o];                                                      \
    float psum = 0.f, psq = 0.f;                                             \
    _Pragma("unroll")                                                        \
    for (int am = 0; am < 4; am++) {                                         \
      _Pragma("unroll")                                                      \
      for (int r = 0; r < 4; r++) {                                          \
        int s = bm0 + wr * 64 + am * 16 + l4 * 4 + r;                        \
        float v = acc[am][BN][r] + bv;                                       \
        v = (s < len) ? v : 0.f;                                             \
        size_t off = ((size_t)(b * SS + s)) * HH + o;                        \
        if (fout) {                                                          \
          fout[off] = (v + resid[off]) * 0.70710678118654752f;               \
        } else {                                                             \
          yout[off] = f2bf(v);                                               \
          psum += v;                                                         \
          psq += v * v;                                                      \
        }                                                                    \
      }                                                                      \
    }                                                                        \
    if (sum) {                                                               \
      psum += __shfl_xor(psum, 16, 64);                                      \
      psum += __shfl_xor(psum, 32, 64);                                      \
      psq  += __shfl_xor(psq, 16, 64);                                       \
      psq  += __shfl_xor(psq, 32, 64);                                       \
      if (l4 == 0) {                                                         \
        atomicAdd(&sum[b * HH + o], psum);                                   \
        atomicAdd(&sumsq[b * HH + o], psq);                                  \
      }                                                                      \
    }                                                                        \
  } while (0)

  if (team == 0) { EPI(0); EPI(1); }
  else           { EPI(2); EPI(3); }
#undef EPI
}

extern "C" void kernel_launch(void* const* d_in, const int* in_sizes, int n_in,
                              void* d_out, int out_size, void* d_ws, size_t ws_size,
                              hipStream_t stream) {
  const float* x    = (const float*)d_in[0];
  const float* sty  = (const float*)d_in[1];
  const int*   lens = (const int*)d_in[2];
  const float* p1w  = (const float*)d_in[3];
  const float* p1b  = (const float*)d_in[4];
  const float* p2w  = (const float*)d_in[5];
  const float* p2b  = (const float*)d_in[6];
  const float* c1v  = (const float*)d_in[7];
  const float* c1g  = (const float*)d_in[8];
  const float* c1b  = (const float*)d_in[9];
  const float* c2v  = (const float*)d_in[10];
  const float* c2g  = (const float*)d_in[11];
  const float* c2b  = (const float*)d_in[12];
  float* out = (float*)d_out;

  char* ws = (char*)d_ws;
  size_t cur = 0;
  auto alloc = [&](size_t bytes) {
    void* p = ws + cur;
    cur += (bytes + 255) & ~(size_t)255;
    return p;
  };
  u16*   wt1  = (u16*)alloc((size_t)3 * HH * HH * 2);
  u16*   wt2  = (u16*)alloc((size_t)3 * HH * HH * 2);
  float* g1   = (float*)alloc(NB * HH * 4);
  float* be1  = (float*)alloc(NB * HH * 4);
  float* g2   = (float*)alloc(NB * HH * 4);
  float* be2  = (float*)alloc(NB * HH * 4);
  float* sum1 = (float*)alloc(NB * HH * 4);
  float* sq1  = (float*)alloc(NB * HH * 4);
  float* sum2 = (float*)alloc(NB * HH * 4);
  float* sq2  = (float*)alloc(NB * HH * 4);
  u16*   z1   = (u16*)alloc((size_t)NB * SP * HH * 2);
  u16*   y1   = (u16*)alloc((size_t)NB * SS * HH * 2);
  u16*   z2   = (u16*)alloc((size_t)NB * SP * HH * 2);

  const int CGRID = NB * (SS / BM) * (HH / BN);   // 8*16*4 = 512

  // zero the 4 stats arrays (contiguous: sum1,sq1,sum2,sq2)
  k_zero<<<(4 * NB * HH + 255) / 256, 256, 0, stream>>>(sum1, 4 * NB * HH);

  // style projections (both)
  k_proj<<<(2 * NB * 2 * HH + 255) / 256, 256, 0, stream>>>(sty, p1w, p1b, p2w, p2b,
                                                            g1, be1, g2, be2);
  // weight norm + bf16 repack (both convs)
  k_wnorm<<<2 * HH, 256, 0, stream>>>(c1v, c1g, c2v, c2g, wt1, wt2);

  // stage 1 stats over x (latency-fixed: float4 x16 unroll, grid 512)
  k_stats_f32<<<NB * SSPLIT1, 256, 0, stream>>>(x, lens, sum1, sq1);

  // z1 = mask * lrelu(adain1(x))  [affine fused from raw stats]
  k_prep_f32<<<NB * (SP * HH / 4 / 256), 256, 0, stream>>>(x, sum1, sq1, g1, be1,
                                                           lens, z1);

  // y1 = (conv1(z1) + b1) * mask (bf16), with fused stage-2 stats
  k_conv<<<CGRID, 512, 0, stream>>>(z1, wt1, c1b, lens, y1,
                                    nullptr, nullptr, sum2, sq2);

  // z2 = mask * lrelu(adain2(y1))  [affine fused from raw stats]
  k_prep_bf16<<<NB * (SP * HH / 4 / 256), 256, 0, stream>>>(y1, sum2, sq2, g2, be2,
                                                            lens, z2);

  // out = ((conv2(z2) + b2) * mask + x) / sqrt(2)
  k_conv<<<CGRID, 512, 0, stream>>>(z2, wt2, c2b, lens, nullptr,
                                    x, out, nullptr, nullptr);
}

// Round 12
// 114.278 us; speedup vs baseline: 1.1714x; 1.1714x over previous
//
#include <hip/hip_runtime.h>

#define NB 8
#define SS 2048
#define HH 512
#define NSTY 128
#define SP (SS + 2)
#define EPSF 1e-5f

#define BM 128
#define BN 128
#define BK 64

typedef __attribute__((ext_vector_type(8))) short short8;
typedef __attribute__((ext_vector_type(4))) float floatx4;
typedef __attribute__((ext_vector_type(4))) unsigned short u16x4;
typedef unsigned short u16;

__device__ __forceinline__ float bf2f(u16 u) {
  union { float f; unsigned int i; } v; v.i = ((unsigned int)u) << 16; return v.f;
}
__device__ __forceinline__ u16 f2bf(float f) {
  union { float f; unsigned int i; } v; v.f = f;
  unsigned int x = v.i;
  return (u16)((x + 0x7fffu + ((x >> 16) & 1u)) >> 16);
}
__device__ __forceinline__ float lrelu(float v) { return v >= 0.f ? v : 0.2f * v; }

__device__ __forceinline__ void gld_lds16(const u16* g, u16* l) {
  __builtin_amdgcn_global_load_lds((const __attribute__((address_space(1))) void*)g,
                                   (__attribute__((address_space(3))) void*)l, 16, 0, 0);
}

// ---------------- fused setup: wnorm (blocks 0..1023) | proj (1024..1087) |
// zero stats (1088..1151). All three independent; one launch. ----------------
__global__ void k_setup(const float* __restrict__ style,
                        const float* __restrict__ p1w, const float* __restrict__ p1b,
                        const float* __restrict__ p2w, const float* __restrict__ p2b,
                        const float* __restrict__ c1v, const float* __restrict__ c1g,
                        const float* __restrict__ c2v, const float* __restrict__ c2g,
                        u16* __restrict__ wt1, u16* __restrict__ wt2,
                        float* __restrict__ g1, float* __restrict__ be1,
                        float* __restrict__ g2, float* __restrict__ be2,
                        float* __restrict__ stats /* sum1 base, 4*NB*HH contig */) {
  int bid = blockIdx.x;
  if (bid < 2 * HH) {
    // ---- weight norm + repack to bf16 [k][o][i] ----
    int o = bid % HH;
    int which = bid / HH;
    const float* v = which ? c2v : c1v;
    const float* g = which ? c2g : c1g;
    u16* wt = which ? wt2 : wt1;
    float s = 0.f;
    for (int e = threadIdx.x; e < HH * 3; e += 256) {
      float x = v[o * HH * 3 + e];
      s += x * x;
    }
    for (int off = 32; off > 0; off >>= 1) s += __shfl_down(s, off, 64);
    __shared__ float red[4];
    int wid = threadIdx.x >> 6, lane = threadIdx.x & 63;
    if (lane == 0) red[wid] = s;
    __syncthreads();
    float tot = red[0] + red[1] + red[2] + red[3];
    float scale = g[o] / sqrtf(tot);
    for (int e = threadIdx.x; e < HH * 3; e += 256) {
      int i = e / 3, k = e % 3;      // v[o][i][k] flat = o*1536 + e
      wt[(k * HH + o) * HH + i] = f2bf(v[o * HH * 3 + e] * scale);
    }
  } else if (bid < 2 * HH + 64) {
    // ---- style projections (both) ----
    int idx = (bid - 2 * HH) * 256 + threadIdx.x;   // 0..16383 exact
    int which = idx / (NB * 2 * HH);
    int r = idx % (NB * 2 * HH);
    int b = r / (2 * HH);
    int j = r % (2 * HH);
    const float* w = which ? p2w : p1w;
    const float* bias = which ? p2b : p1b;
    float acc = bias[j];
    const float* st = style + b * NSTY;
    const float* wr = w + j * NSTY;
    for (int t = 0; t < NSTY; t++) acc += st[t] * wr[t];
    float* gd = which ? g2 : g1;
    float* bd = which ? be2 : be1;
    if (j < HH) gd[b * HH + j] = acc;
    else        bd[b * HH + (j - HH)] = acc;
  } else {
    // ---- zero the 4 stats arrays (sum1,sq1,sum2,sq2 contiguous) ----
    int i = (bid - 2 * HH - 64) * 256 + threadIdx.x;  // 0..16383 exact
    stats[i] = 0.f;
  }
}

// ---------------- masked stats over S (f32 input), latency-fixed ----------------
#define SSPLIT1 64
__global__ void k_stats_f32(const float* __restrict__ x, const int* __restrict__ lens,
                            float* __restrict__ sum, float* __restrict__ sumsq) {
  int b = blockIdx.x & 7;
  int chunk = blockIdx.x >> 3;                     // 0..63
  int s0 = chunk * (SS / SSPLIT1);                 // 32 rows per block
  int h4 = (threadIdx.x & 127) * 4;                // float4 column
  int sr = threadIdx.x >> 7;                       // 0,1
  int len = lens[b];
  float4 sm = {0.f, 0.f, 0.f, 0.f}, sq = {0.f, 0.f, 0.f, 0.f};
#pragma unroll
  for (int i = 0; i < 16; i++) {
    int s = s0 + i * 2 + sr;
    float4 v = *(const float4*)(x + ((long)(b * SS + s)) * HH + h4);
    float m = (s < len) ? 1.f : 0.f;
    v.x *= m; v.y *= m; v.z *= m; v.w *= m;
    sm.x += v.x; sm.y += v.y; sm.z += v.z; sm.w += v.w;
    sq.x += v.x * v.x; sq.y += v.y * v.y; sq.z += v.z * v.z; sq.w += v.w * v.w;
  }
  atomicAdd(&sum[b * HH + h4 + 0], sm.x);
  atomicAdd(&sum[b * HH + h4 + 1], sm.y);
  atomicAdd(&sum[b * HH + h4 + 2], sm.z);
  atomicAdd(&sum[b * HH + h4 + 3], sm.w);
  atomicAdd(&sumsq[b * HH + h4 + 0], sq.x);
  atomicAdd(&sumsq[b * HH + h4 + 1], sq.y);
  atomicAdd(&sumsq[b * HH + h4 + 2], sq.z);
  atomicAdd(&sumsq[b * HH + h4 + 3], sq.w);
}

// ---------------- adain affine from raw stats (inline helper) ----------------
__device__ __forceinline__ void affine4(const float* sum, const float* sumsq,
                                        const float* gam, const float* bet,
                                        int b, int i, float cnt,
                                        float4& av, float4& cv) {
  float4 sm = *(const float4*)(sum + b * HH + i);
  float4 sq = *(const float4*)(sumsq + b * HH + i);
  float4 gv = *(const float4*)(gam + b * HH + i);
  float4 bv = *(const float4*)(bet + b * HH + i);
  float rc = 1.f / cnt;
  float mx = sm.x * rc, my = sm.y * rc, mz = sm.z * rc, mw = sm.w * rc;
  av.x = (1.f + gv.x) * rsqrtf(sq.x * rc - mx * mx + EPSF);
  av.y = (1.f + gv.y) * rsqrtf(sq.y * rc - my * my + EPSF);
  av.z = (1.f + gv.z) * rsqrtf(sq.z * rc - mz * mz + EPSF);
  av.w = (1.f + gv.w) * rsqrtf(sq.w * rc - mw * mw + EPSF);
  cv.x = bv.x - mx * av.x;
  cv.y = bv.y - my * av.y;
  cv.z = bv.z - mz * av.z;
  cv.w = bv.w - mw * av.w;
}

// ---------------- Z prep (f32 src), fused affine, XCD-aligned ----------------
__global__ void k_prep_f32(const float* __restrict__ x,
                           const float* __restrict__ sum, const float* __restrict__ sumsq,
                           const float* __restrict__ gam, const float* __restrict__ bet,
                           const int* __restrict__ lens, u16* __restrict__ z) {
  int b = blockIdx.x & 7;
  int v = (blockIdx.x >> 3) * 256 + threadIdx.x;   // 0..262399 (exact)
  long off = (long)v * 4;                          // elem offset within batch
  int i = (int)(off % HH);
  int r = (int)(off / HH);                         // 0..SP-1
  int s = r - 1;
  int len = lens[b];
  u16x4 outv;
  if (s < 0 || s >= SS || s >= len) {
    outv = (u16x4){0, 0, 0, 0};
  } else {
    float4 av, cv;
    affine4(sum, sumsq, gam, bet, b, i, (float)len, av, cv);
    const float4 xv = *(const float4*)(x + ((long)(b * SS + s)) * HH + i);
    outv.x = f2bf(lrelu(av.x * xv.x + cv.x));
    outv.y = f2bf(lrelu(av.y * xv.y + cv.y));
    outv.z = f2bf(lrelu(av.z * xv.z + cv.z));
    outv.w = f2bf(lrelu(av.w * xv.w + cv.w));
  }
  *(u16x4*)(z + ((long)(b * SP + r)) * HH + i) = outv;
}

// ---------------- Z prep (bf16 src), fused affine, XCD-aligned ----------------
__global__ void k_prep_bf16(const u16* __restrict__ y,
                            const float* __restrict__ sum, const float* __restrict__ sumsq,
                            const float* __restrict__ gam, const float* __restrict__ bet,
                            const int* __restrict__ lens, u16* __restrict__ z) {
  int b = blockIdx.x & 7;
  int v = (blockIdx.x >> 3) * 256 + threadIdx.x;
  long off = (long)v * 4;
  int i = (int)(off % HH);
  int r = (int)(off / HH);
  int s = r - 1;
  int len = lens[b];
  u16x4 outv;
  if (s < 0 || s >= SS || s >= len) {
    outv = (u16x4){0, 0, 0, 0};
  } else {
    float4 av, cv;
    affine4(sum, sumsq, gam, bet, b, i, (float)len, av, cv);
    const u16x4 yv = *(const u16x4*)(y + ((long)(b * SS + s)) * HH + i);
    outv.x = f2bf(lrelu(av.x * bf2f(yv.x) + cv.x));
    outv.y = f2bf(lrelu(av.y * bf2f(yv.y) + cv.y));
    outv.z = f2bf(lrelu(av.z * bf2f(yv.z) + cv.z));
    outv.w = f2bf(lrelu(av.w * bf2f(yv.w) + cv.w));
  }
  *(u16x4*)(z + ((long)(b * SP + r)) * HH + i) = outv;
}

// ---------------- conv1d as flat GEMM: in-block split-K (R10 exact) ----------
// R11 post-mortem: counted-vmcnt BK32 dbuf REGRESSED (48 vs 44.5 us) -- the
// halved MFMA-per-barrier cost more than the counted wait saved. This is the
// proven-best R10 schedule: 2 teams x 12 BK64 steps, drain-0 __syncthreads,
// 64 KB LDS, 2 blocks/CU (VGPR-capped 16 waves/CU ceiling). Rule #20: all
// post-loop acc indices are compile-time literals (team branch is wave-
// uniform). Swizzle slot^(row&7) on both global source col and ds_read addr.
// XCD remap: one batch per XCD (matches k_prep writers).
__global__ __launch_bounds__(512, 4) void k_conv(const u16* __restrict__ z,
                                                 const u16* __restrict__ wt,
                                                 const float* __restrict__ bias,
                                                 const int* __restrict__ lens,
                                                 u16* __restrict__ yout,
                                                 const float* __restrict__ resid,
                                                 float* __restrict__ fout,
                                                 float* __restrict__ sum,
                                                 float* __restrict__ sumsq) {
  // [team][A=0/B=1][128 rows x 64 cols]  = 64 KB total (also f32 scratch)
  __shared__ __align__(16) u16 L[2][2][BM * BK];

  int nwg = gridDim.x;                        // 512, divisible by 8
  int bid = blockIdx.x;
  int t = (bid & 7) * (nwg >> 3) + (bid >> 3);     // XCD-contiguous logical id
  int bn0 = (t % (HH / BN)) * BN; t /= (HH / BN);
  int bm0 = (t % (SS / BM)) * BM; t /= (SS / BM);
  int b = t;                                  // == XCD id (one batch per XCD)

  int tid = threadIdx.x;
  int wave = tid >> 6, lane = tid & 63;
  int team = wave >> 2;                       // 0: K-steps 0..11, 1: 12..23
  int tw = wave & 3;
  int wr = tw >> 1, wc = tw & 1;              // team-internal 2x2 waves (64x64)
  int l15 = lane & 15, l4 = lane >> 4;

  int t256 = tid & 255;                       // index within team
  int trow = t256 >> 3;                       // 0..31 row within round
  int tslot = t256 & 7;                       // 16B slot within 128B row

  u16* LA = &L[team][0][0];
  u16* LB = &L[team][1][0];

  const u16* zb = z + (size_t)b * SP * HH;
  int len = lens[b];
  int kt0 = team * 12;

  floatx4 acc[4][4] = {};

  for (int kt = 0; kt < 12; kt++) {           // this team's 12 K-tiles
    int k0 = (kt0 + kt) * BK;
    const u16* wkb = wt + (size_t)(k0 >> 9) * HH * HH + (k0 & 511);
#pragma unroll
    for (int rr = 0; rr < 4; rr++) {          // A: 128 rows
      int r = rr * 32 + trow;
      int sc = (tslot ^ (r & 7)) * 8;
      gld_lds16(zb + (size_t)(bm0 + r) * HH + k0 + sc, LA + rr * 2048 + t256 * 8);
    }
#pragma unroll
    for (int rr = 0; rr < 4; rr++) {          // B: 128 rows
      int r = rr * 32 + trow;
      int sc = (tslot ^ (r & 7)) * 8;
      gld_lds16(wkb + (size_t)(bn0 + r) * HH + sc, LB + rr * 2048 + t256 * 8);
    }
    __syncthreads();                          // drains vmcnt (both teams)
#pragma unroll
    for (int kk = 0; kk < 2; kk++) {
      short8 afr[4], bfr[4];
#pragma unroll
      for (int i = 0; i < 4; i++) {
        int ar = wr * 64 + i * 16 + l15;
        afr[i] = *(const short8*)&LA[ar * BK + (((kk * 4 + l4) ^ (ar & 7)) * 8)];
      }
#pragma unroll
      for (int j = 0; j < 4; j++) {
        int br = wc * 64 + j * 16 + l15;
        bfr[j] = *(const short8*)&LB[br * BK + (((kk * 4 + l4) ^ (br & 7)) * 8)];
      }
#pragma unroll
      for (int am = 0; am < 4; am++)
#pragma unroll
        for (int bn = 0; bn < 4; bn++)
          acc[am][bn] = __builtin_amdgcn_mfma_f32_16x16x32_bf16(afr[am], bfr[bn], acc[am][bn], 0, 0, 0);
    }
    __syncthreads();
  }

  // ---- cross-team reduction via LDS (reused as f32 scratch) ----
  // STATIC acc indices only (rule #20): team 0 exports cols 2,3; team 1
  // exports cols 0,1. layout: scr[team*2048 + (am*2+bnl)*256 + t256]
  floatx4* scr = (floatx4*)&L[0][0][0];       // 4096 float4 = 64 KB
  floatx4* my = scr + (size_t)team * 2048;
  if (team == 0) {
#pragma unroll
    for (int am = 0; am < 4; am++) {
      my[(am * 2 + 0) * 256 + t256] = acc[am][2];
      my[(am * 2 + 1) * 256 + t256] = acc[am][3];
    }
  } else {
#pragma unroll
    for (int am = 0; am < 4; am++) {
      my[(am * 2 + 0) * 256 + t256] = acc[am][0];
      my[(am * 2 + 1) * 256 + t256] = acc[am][1];
    }
  }
  __syncthreads();
  const floatx4* other = scr + (size_t)(team ^ 1) * 2048;
  if (team == 0) {
#pragma unroll
    for (int am = 0; am < 4; am++) {
      acc[am][0] += other[(am * 2 + 0) * 256 + t256];
      acc[am][1] += other[(am * 2 + 1) * 256 + t256];
    }
  } else {
#pragma unroll
    for (int am = 0; am < 4; am++) {
      acc[am][2] += other[(am * 2 + 0) * 256 + t256];
      acc[am][3] += other[(am * 2 + 1) * 256 + t256];
    }
  }

  // ---- epilogue: literal BN via macro, team branch is wave-uniform ----
#define EPI(BN) do {                                                         \
    int o = bn0 + wc * 64 + (BN) * 16 + l15;                                 \
    float bv = bias[o];                                                      \
    float psum = 0.f, psq = 0.f;                                             \
    _Pragma("unroll")                                                        \
    for (int am = 0; am < 4; am++) {                                         \
      _Pragma("unroll")                                                      \
      for (int r = 0; r < 4; r++) {                                          \
        int s = bm0 + wr * 64 + am * 16 + l4 * 4 + r;                        \
        float v = acc[am][BN][r] + bv;                                       \
        v = (s < len) ? v : 0.f;                                             \
        size_t off = ((size_t)(b * SS + s)) * HH + o;                        \
        if (fout) {                                                          \
          fout[off] = (v + resid[off]) * 0.70710678118654752f;               \
        } else {                                                             \
          yout[off] = f2bf(v);                                               \
          psum += v;                                                         \
          psq += v * v;                                                      \
        }                                                                    \
      }                                                                      \
    }                                                                        \
    if (sum) {                                                               \
      psum += __shfl_xor(psum, 16, 64);                                      \
      psum += __shfl_xor(psum, 32, 64);                                      \
      psq  += __shfl_xor(psq, 16, 64);                                       \
      psq  += __shfl_xor(psq, 32, 64);                                       \
      if (l4 == 0) {                                                         \
        atomicAdd(&sum[b * HH + o], psum);                                   \
        atomicAdd(&sumsq[b * HH + o], psq);                                  \
      }                                                                      \
    }                                                                        \
  } while (0)

  if (team == 0) { EPI(0); EPI(1); }
  else           { EPI(2); EPI(3); }
#undef EPI
}

extern "C" void kernel_launch(void* const* d_in, const int* in_sizes, int n_in,
                              void* d_out, int out_size, void* d_ws, size_t ws_size,
                              hipStream_t stream) {
  const float* x    = (const float*)d_in[0];
  const float* sty  = (const float*)d_in[1];
  const int*   lens = (const int*)d_in[2];
  const float* p1w  = (const float*)d_in[3];
  const float* p1b  = (const float*)d_in[4];
  const float* p2w  = (const float*)d_in[5];
  const float* p2b  = (const float*)d_in[6];
  const float* c1v  = (const float*)d_in[7];
  const float* c1g  = (const float*)d_in[8];
  const float* c1b  = (const float*)d_in[9];
  const float* c2v  = (const float*)d_in[10];
  const float* c2g  = (const float*)d_in[11];
  const float* c2b  = (const float*)d_in[12];
  float* out = (float*)d_out;

  char* ws = (char*)d_ws;
  size_t cur = 0;
  auto alloc = [&](size_t bytes) {
    void* p = ws + cur;
    cur += (bytes + 255) & ~(size_t)255;
    return p;
  };
  u16*   wt1  = (u16*)alloc((size_t)3 * HH * HH * 2);
  u16*   wt2  = (u16*)alloc((size_t)3 * HH * HH * 2);
  float* g1   = (float*)alloc(NB * HH * 4);
  float* be1  = (float*)alloc(NB * HH * 4);
  float* g2   = (float*)alloc(NB * HH * 4);
  float* be2  = (float*)alloc(NB * HH * 4);
  float* sum1 = (float*)alloc(NB * HH * 4);
  float* sq1  = (float*)alloc(NB * HH * 4);
  float* sum2 = (float*)alloc(NB * HH * 4);
  float* sq2  = (float*)alloc(NB * HH * 4);
  u16*   z1   = (u16*)alloc((size_t)NB * SP * HH * 2);
  u16*   y1   = (u16*)alloc((size_t)NB * SS * HH * 2);
  u16*   z2   = (u16*)alloc((size_t)NB * SP * HH * 2);

  const int CGRID = NB * (SS / BM) * (HH / BN);   // 8*16*4 = 512

  // fused setup: wnorm (1024 blocks) + proj (64) + stats-zero (64)
  k_setup<<<2 * HH + 128, 256, 0, stream>>>(sty, p1w, p1b, p2w, p2b,
                                            c1v, c1g, c2v, c2g,
                                            wt1, wt2, g1, be1, g2, be2, sum1);

  // stage 1 stats over x (latency-fixed: float4 x16 unroll, grid 512)
  k_stats_f32<<<NB * SSPLIT1, 256, 0, stream>>>(x, lens, sum1, sq1);

  // z1 = mask * lrelu(adain1(x))  [affine fused from raw stats]
  k_prep_f32<<<NB * (SP * HH / 4 / 256), 256, 0, stream>>>(x, sum1, sq1, g1, be1,
                                                           lens, z1);

  // y1 = (conv1(z1) + b1) * mask (bf16), with fused stage-2 stats
  k_conv<<<CGRID, 512, 0, stream>>>(z1, wt1, c1b, lens, y1,
                                    nullptr, nullptr, sum2, sq2);

  // z2 = mask * lrelu(adain2(y1))  [affine fused from raw stats]
  k_prep_bf16<<<NB * (SP * HH / 4 / 256), 256, 0, stream>>>(y1, sum2, sq2, g2, be2,
                                                            lens, z2);

  // out = ((conv2(z2) + b2) * mask + x) / sqrt(2)
  k_conv<<<CGRID, 512, 0, stream>>>(z2, wt2, c2b, lens, nullptr,
                                    x, out, nullptr, nullptr);
}